// Round 1
// 582.747 us; speedup vs baseline: 1.0131x; 1.0131x over previous
//
#include <hip/hip_runtime.h>
#include <math.h>

#define Bc 4
#define Nc 256
#define Tc 128
#define Dc 512
#define Hc 8
#define HDc 64

typedef float f4v __attribute__((ext_vector_type(4)));

// swizzled float4-unit index for 64x64 float tile stored as 1024 float4s
#define SWZ(row, k4) (((row) << 4) | ((k4) ^ (((row) >> 2) & 15)))

// ---------------- Kernel 1: x_repr = mean over T -------------------------
__global__ __launch_bounds__(256) void mean_kernel(const float* __restrict__ x,
                                                   float* __restrict__ xr) {
    const int bn = blockIdx.x;
    const int col = threadIdx.x & 127;
    const int half = threadIdx.x >> 7;
    const f4v* xp = (const f4v*)x + (size_t)bn * (Tc * Dc / 4)
                    + (size_t)(half * 64) * (Dc / 4) + col;
    f4v a[8];
#pragma unroll
    for (int u = 0; u < 8; ++u) a[u] = (f4v)(0.f);
    for (int t = 0; t < 64; t += 8) {
#pragma unroll
        for (int u = 0; u < 8; ++u)
            a[u] += __builtin_nontemporal_load(xp + (size_t)(t + u) * (Dc / 4));
    }
    f4v s = ((a[0] + a[1]) + (a[2] + a[3])) + ((a[4] + a[5]) + (a[6] + a[7]));
    __shared__ f4v red[256];
    red[threadIdx.x] = s;
    __syncthreads();
    if (threadIdx.x < 128) {
        f4v r = (red[threadIdx.x] + red[threadIdx.x + 128]) * (1.0f / Tc);
        ((f4v*)xr)[(size_t)bn * (Dc / 4) + threadIdx.x] = r;
    }
}

// ---------------- GEMM core with register-prefetch pipeline --------------
__device__ __forceinline__ void gemm_core(const float* __restrict__ A,
                                          const float* __restrict__ W,
                                          int i0, int j0, float acc[4][4]) {
    __shared__ float4 As4[1024];
    __shared__ float4 Ws4[1024];
    const int tid = threadIdx.x;
    const int ty = tid >> 4, tx = tid & 15;
    float4 pa[4], pw[4];
#pragma unroll
    for (int p = 0; p < 4; ++p) {
        pa[p] = *(const float4*)&A[(size_t)(i0 + p * 16 + ty) * Dc + tx * 4];
        pw[p] = *(const float4*)&W[(size_t)(j0 + p * 16 + ty) * Dc + tx * 4];
    }
    for (int kb = 0; kb < 8; ++kb) {
#pragma unroll
        for (int p = 0; p < 4; ++p) {
            As4[SWZ(p * 16 + ty, tx)] = pa[p];
            Ws4[SWZ(p * 16 + ty, tx)] = pw[p];
        }
        __syncthreads();
        if (kb < 7) {
            const int k0 = (kb + 1) * 64;
#pragma unroll
            for (int p = 0; p < 4; ++p) {
                pa[p] = *(const float4*)&A[(size_t)(i0 + p * 16 + ty) * Dc + k0 + tx * 4];
                pw[p] = *(const float4*)&W[(size_t)(j0 + p * 16 + ty) * Dc + k0 + tx * 4];
            }
        }
#pragma unroll
        for (int kk4 = 0; kk4 < 16; ++kk4) {
            float4 a[4], w[4];
#pragma unroll
            for (int q = 0; q < 4; ++q) a[q] = As4[SWZ(ty * 4 + q, kk4)];
#pragma unroll
            for (int c = 0; c < 4; ++c) w[c] = Ws4[SWZ(tx * 4 + c, kk4)];
#pragma unroll
            for (int q = 0; q < 4; ++q)
#pragma unroll
                for (int c = 0; c < 4; ++c) {
                    acc[q][c] += a[q].x * w[c].x;
                    acc[q][c] += a[q].y * w[c].y;
                    acc[q][c] += a[q].z * w[c].z;
                    acc[q][c] += a[q].w * w[c].w;
                }
        }
        __syncthreads();
    }
}

// Fused QKV: grid (16, 24). K stored TRANSPOSED: Kt[((b*8+h)*64+hd)*256+n]
__global__ __launch_bounds__(256) void qkv_kernel(
    const float* __restrict__ xr, const float* __restrict__ Wq, const float* __restrict__ bq,
    const float* __restrict__ Wk, const float* __restrict__ bk,
    const float* __restrict__ Wv, const float* __restrict__ bv,
    float* __restrict__ Yq, float* __restrict__ Kt, float* __restrict__ Yv) {
    const int it = blockIdx.x;
    const int mat = blockIdx.y >> 3;
    const int jt = blockIdx.y & 7;
    const float* W = (mat == 0) ? Wq : (mat == 1) ? Wk : Wv;
    const float* bias = (mat == 0) ? bq : (mat == 1) ? bk : bv;
    const int i0 = it * 64, j0 = jt * 64;
    float acc[4][4] = {{0.f}};
    gemm_core(xr, W, i0, j0, acc);
    const int ty = threadIdx.x >> 4, tx = threadIdx.x & 15;
    if (mat == 1) {
        const int b = i0 >> 8;
        const int n0 = (i0 & 255) + ty * 4;
#pragma unroll
        for (int c = 0; c < 4; ++c) {
            const int j = j0 + tx * 4 + c;
            const float bj = bias[j];
            float4 v = make_float4(acc[0][c] + bj, acc[1][c] + bj,
                                   acc[2][c] + bj, acc[3][c] + bj);
            *(float4*)&Kt[(((size_t)b * Hc + jt) * HDc + (tx * 4 + c)) * Nc + n0] = v;
        }
    } else {
        float* Y = (mat == 0) ? Yq : Yv;
#pragma unroll
        for (int r = 0; r < 4; ++r) {
            const int i = i0 + ty * 4 + r;
            const int j = j0 + tx * 4;
            float4 o = make_float4(acc[r][0] + bias[j + 0], acc[r][1] + bias[j + 1],
                                   acc[r][2] + bias[j + 2], acc[r][3] + bias[j + 3]);
            *(float4*)&Y[(size_t)i * Dc + j] = o;
        }
    }
}

// ---------------- Kernel 3: attention, 4 queries per wave ----------------
// grid: 512 blocks = 32 bh x 16 query-groups; 256 threads = 4 waves.
// Each wave owns 4 query rows: every K/V load is reused 4x in registers.
// Bias MLP restructured: k4-outer / pairs-inner, float4 LDS reads
// (48 LDS read instrs/thread instead of 3072 scalar ds_read_b32).
__global__ __launch_bounds__(256) void attn_kernel(
    const float* __restrict__ Yq, const float* __restrict__ Kt,
    const float* __restrict__ Yv, const float* __restrict__ coords,
    const int* __restrict__ mask, const float* __restrict__ Wd1,
    const float* __restrict__ bd1, const float* __restrict__ Wd2,
    const float* __restrict__ bd2, float* __restrict__ attnO) {
    const int bh = blockIdx.x >> 4;        // 0..31
    const int g = blockIdx.x & 15;         // query group (16 rows)
    const int b = bh >> 3, h = bh & 7;
    const int tid = threadIdx.x;
    const int wid = tid >> 6, lane = tid & 63;
    const int n_base = g * 16;
    const int q0 = wid * 4;                // local query index of this wave

    __shared__ float sq[16][64];           // q rows, pre-scaled
    __shared__ float sw[16][256];          // softmax numerators
    __shared__ float slat[256], slon[256], scl[256];
    __shared__ __align__(16) float swd1[64];
    __shared__ __align__(16) float sbd1[64];
    __shared__ __align__(16) float swd2[64];
    __shared__ int smk[256];

    {
        const float DEG = 0.017453292519943295f;
        float la = coords[((size_t)b * Nc + tid) * 2 + 0] * DEG;
        float lo = coords[((size_t)b * Nc + tid) * 2 + 1] * DEG;
        slat[tid] = la; slon[tid] = lo; scl[tid] = __cosf(la);
        smk[tid] = mask[(size_t)b * Nc + tid];
        if (tid < 64) {
            swd1[tid] = Wd1[tid];
            sbd1[tid] = bd1[tid];
            swd2[tid] = Wd2[h * 64 + tid];
        }
#pragma unroll
        for (int r = 0; r < 4; ++r) {
            const int idx = r * 256 + tid;
            const int nl = idx >> 6, d = idx & 63;
            sq[nl][d] = Yq[((size_t)(b * Nc + n_base + nl)) * Dc + h * HDc + d] * 0.125f;
        }
    }
    __syncthreads();

    // ---- scores: lane owns m-strip lane*4..+3 for 4 queries ----
    const float4* ktp = (const float4*)(Kt + (size_t)bh * HDc * Nc);
    f4v acc[4];
#pragma unroll
    for (int j = 0; j < 4; ++j) acc[j] = (f4v)(0.f);
#pragma unroll 8
    for (int k = 0; k < 64; ++k) {
        const float4 kv = ktp[k * 64 + lane];
        const f4v kvv = {kv.x, kv.y, kv.z, kv.w};
#pragma unroll
        for (int j = 0; j < 4; ++j) acc[j] += sq[q0 + j][k] * kvv;
    }

    // ---- haversine distances for all 16 (j, jm) pairs ----
    const int mbase = lane * 4;
    float mlat[4], mlon[4], mcl[4];
    int mk[4];
#pragma unroll
    for (int jm = 0; jm < 4; ++jm) {
        mlat[jm] = slat[mbase + jm]; mlon[jm] = slon[mbase + jm];
        mcl[jm] = scl[mbase + jm];   mk[jm] = smk[mbase + jm];
    }
    float dist[4][4];
#pragma unroll
    for (int j = 0; j < 4; ++j) {
        const int n = n_base + q0 + j;
        const float lat1 = slat[n], lon1 = slon[n], cl1 = scl[n];
#pragma unroll
        for (int jm = 0; jm < 4; ++jm) {
            float sdlat = __sinf((mlat[jm] - lat1) * 0.5f);
            float sdlon = __sinf((mlon[jm] - lon1) * 0.5f);
            float a = sdlat * sdlat + cl1 * mcl[jm] * sdlon * sdlon;
            a = fminf(fmaxf(a, 0.f), 1.f);
            dist[j][jm] = 12742.0f * atan2f(sqrtf(a), sqrtf(1.0f - a));
        }
    }

    // ---- MLP bias: k4-outer, pairs-inner. Scalar adds in strict
    //      k-ascending order per pair => FP-identical to previous kernel.
    float bias[4][4];
#pragma unroll
    for (int j = 0; j < 4; ++j)
#pragma unroll
        for (int jm = 0; jm < 4; ++jm) bias[j][jm] = 0.f;
#pragma unroll 4
    for (int k4 = 0; k4 < 16; ++k4) {
        const float4 w1 = *(const float4*)&swd1[k4 * 4];
        const float4 b1 = *(const float4*)&sbd1[k4 * 4];
        const float4 w2 = *(const float4*)&swd2[k4 * 4];
#pragma unroll
        for (int j = 0; j < 4; ++j)
#pragma unroll
            for (int jm = 0; jm < 4; ++jm) {
                const float d = dist[j][jm];
                float bacc = bias[j][jm];
                bacc += fmaxf(d * w1.x + b1.x, 0.f) * w2.x;
                bacc += fmaxf(d * w1.y + b1.y, 0.f) * w2.y;
                bacc += fmaxf(d * w1.z + b1.z, 0.f) * w2.z;
                bacc += fmaxf(d * w1.w + b1.w, 0.f) * w2.w;
                bias[j][jm] = bacc;
            }
    }

    // ---- mask, softmax per query ----
    float inv[4];
    const float bd2h = bd2[h];
#pragma unroll
    for (int j = 0; j < 4; ++j) {
        float s[4];
#pragma unroll
        for (int jm = 0; jm < 4; ++jm) {
            s[jm] = acc[j][jm] + bias[j][jm] + bd2h;
            if (mk[jm] == 0) s[jm] = -1e30f;
        }
        float mx = fmaxf(fmaxf(s[0], s[1]), fmaxf(s[2], s[3]));
#pragma unroll
        for (int off = 32; off > 0; off >>= 1) mx = fmaxf(mx, __shfl_xor(mx, off, 64));
        float e0 = __expf(s[0] - mx), e1 = __expf(s[1] - mx);
        float e2 = __expf(s[2] - mx), e3 = __expf(s[3] - mx);
        ((float4*)sw[q0 + j])[lane] = make_float4(e0, e1, e2, e3);
        float sum = e0 + e1 + e2 + e3;
#pragma unroll
        for (int off = 32; off > 0; off >>= 1) sum += __shfl_xor(sum, off, 64);
        inv[j] = 1.0f / sum;
    }
    __syncthreads();

    // ---- PV: lane -> (mo, d4); each V load reused for 4 queries ----
    const int mo = lane >> 4, d4 = lane & 15;
    const float* vbase = Yv + (size_t)b * Nc * Dc + h * HDc + d4 * 4;
    f4v o[4];
#pragma unroll
    for (int j = 0; j < 4; ++j) o[j] = (f4v)(0.f);
#pragma unroll 8
    for (int mq = 0; mq < 64; ++mq) {
        const int m = mq * 4 + mo;
        const f4v v = *(const f4v*)&vbase[(size_t)m * Dc];
#pragma unroll
        for (int j = 0; j < 4; ++j) o[j] += sw[q0 + j][m] * v;
    }
#pragma unroll
    for (int j = 0; j < 4; ++j) {
#pragma unroll
        for (int off = 16; off <= 32; off <<= 1) {
            o[j].x += __shfl_xor(o[j].x, off, 64);
            o[j].y += __shfl_xor(o[j].y, off, 64);
            o[j].z += __shfl_xor(o[j].z, off, 64);
            o[j].w += __shfl_xor(o[j].w, off, 64);
        }
        if (mo == 0) {
            const int n = n_base + q0 + j;
            f4v r = o[j] * inv[j];
            *(f4v*)&attnO[((size_t)(b * Nc + n)) * Dc + h * HDc + d4 * 4] = r;
        }
    }
}

// ---------------- Kernel 4: O-projection fused with T-broadcast ----------
__global__ __launch_bounds__(256) void oproj_bcast_kernel(
    const float* __restrict__ attnI, const float* __restrict__ Wo,
    const float* __restrict__ bo, float* __restrict__ out) {
    const int i0 = blockIdx.x * 64, j0 = blockIdx.y * 64;
    const int z = blockIdx.z;
    float acc[4][4] = {{0.f}};
    gemm_core(attnI, Wo, i0, j0, acc);

    __shared__ f4v tile[1024];  // 64 rows x 16 float4
    const int ty = threadIdx.x >> 4, tx = threadIdx.x & 15;
#pragma unroll
    for (int q = 0; q < 4; ++q) {
        const int j = j0 + tx * 4;
        f4v v;
        v.x = acc[q][0] + bo[j + 0]; v.y = acc[q][1] + bo[j + 1];
        v.z = acc[q][2] + bo[j + 2]; v.w = acc[q][3] + bo[j + 3];
        tile[(ty * 4 + q) * 16 + tx] = v;
    }
    __syncthreads();

    const int d4 = threadIdx.x & 15;
    const int sub = threadIdx.x >> 4;
    for (int r = 0; r < 64; ++r) {
        const f4v val = tile[r * 16 + d4];
        float* rowbase = out + (size_t)(i0 + r) * Tc * Dc + j0;
#pragma unroll
        for (int tt = 0; tt < 4; ++tt) {
            const int t = z * 64 + tt * 16 + sub;
            __builtin_nontemporal_store(val, (f4v*)(rowbase + (size_t)t * Dc) + d4);
        }
    }
}

extern "C" void kernel_launch(void* const* d_in, const int* in_sizes, int n_in,
                              void* d_out, int out_size, void* d_ws, size_t ws_size,
                              hipStream_t stream) {
    const float* x      = (const float*)d_in[0];
    const float* coords = (const float*)d_in[1];
    const int*   smask  = (const int*)d_in[2];
    const float* Wq = (const float*)d_in[3];  const float* bq = (const float*)d_in[4];
    const float* Wk = (const float*)d_in[5];  const float* bk = (const float*)d_in[6];
    const float* Wv = (const float*)d_in[7];  const float* bv = (const float*)d_in[8];
    const float* Wo = (const float*)d_in[9];  const float* bo = (const float*)d_in[10];
    const float* Wd1 = (const float*)d_in[11]; const float* bd1 = (const float*)d_in[12];
    const float* Wd2 = (const float*)d_in[13]; const float* bd2 = (const float*)d_in[14];
    float* out = (float*)d_out;

    float* ws    = (float*)d_ws;
    const size_t BND = (size_t)Bc * Nc * Dc;  // 524288
    float* xr    = ws;
    float* Yq    = xr + BND;
    float* Kt    = Yq + BND;   // transposed K
    float* Yv    = Kt + BND;
    float* attn  = Yv + BND;

    mean_kernel<<<Bc * Nc, 256, 0, stream>>>(x, xr);
    qkv_kernel<<<dim3(16, 24), 256, 0, stream>>>(xr, Wq, bq, Wk, bk, Wv, bv, Yq, Kt, Yv);
    attn_kernel<<<32 * 16, 256, 0, stream>>>(Yq, Kt, Yv, coords, smask,
                                             Wd1, bd1, Wd2, bd2, attn);
    oproj_bcast_kernel<<<dim3(16, 8, 2), 256, 0, stream>>>(attn, Wo, bo, out);
}